// Round 12
// baseline (234.702 us; speedup 1.0000x reference)
//
#include <hip/hip_runtime.h>

#define NN 50000
#define NE 800000
#define NB 512
#define DIN 128
#define DD2 200
#define C1 100
#define C2 20
#define DHH 64
#define HH1 128
#define HH2 32
#define KD 201      // fusion inner dim per i (200 + 1)
#define KDP 204     // padded row stride for d1ext
#define NU 2688     // 21 * 128
#define SCB 196     // scan blocks: ceil(50000/256)
#define NCT 7       // col tiles of 16 covering 100 (112 padded)
#define NTILE 3125  // 50000 / 16 row tiles
#define GB1 782     // gemm1 blocks in k_front
#define FPB 3125    // fillpos blocks in k_front
#define PS1 128     // t1 fp8 row stride (bytes), 64B-aligned rows

typedef short sh8 __attribute__((ext_vector_type(8)));
typedef float f32x4 __attribute__((ext_vector_type(4)));

__device__ __forceinline__ unsigned short f2bf(float x) {
    unsigned u = __float_as_uint(x);
    unsigned r = (u + 0x7fffu + ((u >> 16) & 1u)) >> 16;   // RNE
    return (unsigned short)r;
}
__device__ __forceinline__ float bf_lo(unsigned u) { return __uint_as_float(u << 16); }
__device__ __forceinline__ float bf_hi(unsigned u) { return __uint_as_float(u & 0xffff0000u); }

// ---------------- init: pack gc1_W into B-fragments + zero cnt/hgs/dcount ----------------
__global__ void k_packB_init(const float* __restrict__ W, unsigned short* __restrict__ Bf,
                             int* __restrict__ cnt, float* __restrict__ hgs,
                             int* __restrict__ dcount) {
    int idx = blockIdx.x * 256 + threadIdx.x;
    if (idx < NCT * 4 * 64) {
        int lane = idx & 63;
        int kc = (idx >> 6) & 3;
        int ct = idx >> 8;
        int col = ct * 16 + (lane & 15);
        int k0 = kc * 32 + (lane >> 4) * 8;
        unsigned short* outp = Bf + (size_t)idx * 8;
        #pragma unroll
        for (int e = 0; e < 8; ++e) {
            float v = (col < C1) ? W[(k0 + e) * C1 + col] : 0.f;
            outp[e] = f2bf(v);
        }
    }
    if (idx < NN) cnt[idx] = 0;
    if (idx < NB * C2) hgs[idx] = 0.f;
    if (idx == 0) *dcount = 0;
}

// ---------------- fused front: gemm1 (MFMA, fp8-out) || fillpos (atomic CSR pass 1) ----------------
__global__ __launch_bounds__(256) void k_front(const float* __restrict__ feat,
                                               const unsigned short* __restrict__ Bf,
                                               unsigned char* __restrict__ t1f8,
                                               const int* __restrict__ dst,
                                               int* __restrict__ cnt,
                                               int* __restrict__ pos) {
    if (blockIdx.x >= GB1) {
        int e = (blockIdx.x - GB1) * 256 + threadIdx.x;
        if (e < NE) pos[e] = atomicAdd(&cnt[dst[e]], 1);
        return;
    }
    __shared__ sh8 sB[NCT][4][64];       // 28 KB
    const int tid = threadIdx.x;
    {
        const uint4* srcp = (const uint4*)Bf;
        uint4* dstp = (uint4*)&sB[0][0][0];
        for (int i = tid; i < NCT * 4 * 64; i += 256) dstp[i] = srcp[i];
    }
    __syncthreads();
    const int w = tid >> 6, lane = tid & 63;
    const int ri = lane & 15;            // A row within tile / D col low
    const int kg = lane >> 4;            // 0..3
    for (int tile = blockIdx.x * 4 + w; tile < NTILE; tile += GB1 * 4) {
        const int n = tile * 16 + ri;
        f32x4 acc[NCT];
        #pragma unroll
        for (int ct = 0; ct < NCT; ++ct) acc[ct] = (f32x4){0.f, 0.f, 0.f, 0.f};
        #pragma unroll
        for (int kc = 0; kc < 4; ++kc) {
            const float* ap = feat + (size_t)n * DIN + kc * 32 + kg * 8;
            float4 a0 = *(const float4*)ap;
            float4 a1 = *(const float4*)(ap + 4);
            union { sh8 v; unsigned short u[8]; } af;
            af.u[0] = f2bf(a0.x); af.u[1] = f2bf(a0.y);
            af.u[2] = f2bf(a0.z); af.u[3] = f2bf(a0.w);
            af.u[4] = f2bf(a1.x); af.u[5] = f2bf(a1.y);
            af.u[6] = f2bf(a1.z); af.u[7] = f2bf(a1.w);
            #pragma unroll
            for (int ct = 0; ct < NCT; ++ct)
                acc[ct] = __builtin_amdgcn_mfma_f32_16x16x32_bf16(
                    af.v, sB[ct][kc][lane], acc[ct], 0, 0, 0);
        }
        const int rbase = tile * 16 + kg * 4;
        #pragma unroll
        for (int ct = 0; ct < NCT; ++ct) {
            int col = ct * 16 + ri;
            if (col < C1) {
                #pragma unroll
                for (int r = 0; r < 4; ++r) {
                    int pk = __builtin_amdgcn_cvt_pk_fp8_f32(acc[ct][r], acc[ct][r], 0, false);
                    t1f8[(size_t)(rbase + r) * PS1 + col] = (unsigned char)(pk & 0xFF);
                }
            }
        }
    }
}

// ---------------- single-dispatch scan: per-block scan + last-block finalize ----------------
__global__ void k_scan(const int* __restrict__ cnt, int* __restrict__ rp_part,
                       int* __restrict__ bsum, int* __restrict__ row_ptr,
                       int* __restrict__ dcount) {
    __shared__ int wsum[4];
    __shared__ int amLast;
    const int tid = threadIdx.x;          // 256
    const int lane = tid & 63, wid = tid >> 6;
    int i = blockIdx.x * 256 + tid;
    int v = (i < NN) ? cnt[i] : 0;
    int x = v;
    #pragma unroll
    for (int d = 1; d < 64; d <<= 1) {
        int t = __shfl_up(x, d, 64);
        if (lane >= d) x += t;
    }
    if (lane == 63) wsum[wid] = x;
    __syncthreads();
    int wpref = 0;
    #pragma unroll
    for (int w = 0; w < 4; ++w) if (w < wid) wpref += wsum[w];
    if (i < NN) rp_part[i] = wpref + x - v;
    if (tid == 255) bsum[blockIdx.x] = wpref + x;
    // last block finalizes bsum -> exclusive offsets
    __threadfence();
    if (tid == 0) amLast = (atomicAdd(dcount, 1) == SCB - 1);
    __syncthreads();
    if (amLast) {
        int bv = (tid < SCB) ? atomicAdd(&bsum[tid], 0) : 0;   // coherent read
        int bx = bv;
        #pragma unroll
        for (int d = 1; d < 64; d <<= 1) {
            int t = __shfl_up(bx, d, 64);
            if (lane >= d) bx += t;
        }
        __syncthreads();
        if (lane == 63) wsum[wid] = bx;
        __syncthreads();
        int bpref = 0;
        #pragma unroll
        for (int w = 0; w < 4; ++w) if (w < wid) bpref += wsum[w];
        if (tid < SCB) bsum[tid] = bpref + bx - bv;
        if (tid == 255) row_ptr[NN] = bpref + bx;
    }
}

// ---------------- finalize row_ptr + scatter (no atomics) ----------------
__global__ void k_scat3(const int* __restrict__ src, const int* __restrict__ dst,
                        const int* __restrict__ rp_part, const int* __restrict__ bsum,
                        const int* __restrict__ pos, int* __restrict__ elist,
                        int* __restrict__ row_ptr) {
    int i = blockIdx.x * 256 + threadIdx.x;
    if (i < NN) row_ptr[i] = rp_part[i] + bsum[i >> 8];
    if (i < NE) {
        int d = dst[i];
        elist[rp_part[d] + bsum[d >> 8] + pos[i]] = src[i];
    }
}

// ---------------- agg1: fp8 CSR gather-mean + bias + relu -> packed bf16 h1b ----------------
// wave per node, lane l<50 handles channels 2l,2l+1 (2B fp8 pair per edge).
__global__ __launch_bounds__(256) void k_agg1(const unsigned char* __restrict__ t1f8,
                                              const int* __restrict__ row_ptr,
                                              const int* __restrict__ elist,
                                              const float* __restrict__ b1,
                                              unsigned* __restrict__ h1b) {
    const int tid = threadIdx.x;
    const int w = tid >> 6, l = tid & 63;
    const int n = blockIdx.x * 4 + w;
    if (n >= NN || l >= 50) return;
    const int e0 = row_ptr[n], e1 = row_ptr[n + 1];
    const int co = 2 * l;
    float acc0 = 0.f, acc1 = 0.f;
    int e = e0;
    for (; e + 7 < e1; e += 8) {
        int s0 = elist[e],     s1 = elist[e + 1], s2 = elist[e + 2], s3 = elist[e + 3];
        int s4 = elist[e + 4], s5 = elist[e + 5], s6 = elist[e + 6], s7 = elist[e + 7];
        int u0 = *(const unsigned short*)(t1f8 + (size_t)s0 * PS1 + co);
        int u1 = *(const unsigned short*)(t1f8 + (size_t)s1 * PS1 + co);
        int u2 = *(const unsigned short*)(t1f8 + (size_t)s2 * PS1 + co);
        int u3 = *(const unsigned short*)(t1f8 + (size_t)s3 * PS1 + co);
        int u4 = *(const unsigned short*)(t1f8 + (size_t)s4 * PS1 + co);
        int u5 = *(const unsigned short*)(t1f8 + (size_t)s5 * PS1 + co);
        int u6 = *(const unsigned short*)(t1f8 + (size_t)s6 * PS1 + co);
        int u7 = *(const unsigned short*)(t1f8 + (size_t)s7 * PS1 + co);
        acc0 += __builtin_amdgcn_cvt_f32_fp8(u0, 0); acc1 += __builtin_amdgcn_cvt_f32_fp8(u0, 1);
        acc0 += __builtin_amdgcn_cvt_f32_fp8(u1, 0); acc1 += __builtin_amdgcn_cvt_f32_fp8(u1, 1);
        acc0 += __builtin_amdgcn_cvt_f32_fp8(u2, 0); acc1 += __builtin_amdgcn_cvt_f32_fp8(u2, 1);
        acc0 += __builtin_amdgcn_cvt_f32_fp8(u3, 0); acc1 += __builtin_amdgcn_cvt_f32_fp8(u3, 1);
        acc0 += __builtin_amdgcn_cvt_f32_fp8(u4, 0); acc1 += __builtin_amdgcn_cvt_f32_fp8(u4, 1);
        acc0 += __builtin_amdgcn_cvt_f32_fp8(u5, 0); acc1 += __builtin_amdgcn_cvt_f32_fp8(u5, 1);
        acc0 += __builtin_amdgcn_cvt_f32_fp8(u6, 0); acc1 += __builtin_amdgcn_cvt_f32_fp8(u6, 1);
        acc0 += __builtin_amdgcn_cvt_f32_fp8(u7, 0); acc1 += __builtin_amdgcn_cvt_f32_fp8(u7, 1);
    }
    for (; e < e1; ++e) {
        int u = *(const unsigned short*)(t1f8 + (size_t)elist[e] * PS1 + co);
        acc0 += __builtin_amdgcn_cvt_f32_fp8(u, 0);
        acc1 += __builtin_amdgcn_cvt_f32_fp8(u, 1);
    }
    int deg = e1 - e0;
    float d = (float)(deg > 0 ? deg : 1);
    float v0 = fmaxf(acc0 / d + b1[co], 0.f);
    float v1 = fmaxf(acc1 / d + b1[co + 1], 0.f);
    h1b[(size_t)n * 50 + l] = (unsigned)f2bf(v0) | ((unsigned)f2bf(v1) << 16);
}

// ---------------- GCN layer 2 GEMM: t2 = h1 @ gc2_W ----------------
__global__ void k_gemm2(const unsigned* __restrict__ h1b, const float* __restrict__ W,
                        float* __restrict__ t2) {
    __shared__ float sW[C1 * C2];       // 8 KB
    __shared__ float sr[16][C1];        // 6.4 KB
    for (int idx = threadIdx.x; idx < C1 * C2; idx += 320) sW[idx] = W[idx];
    int ln = threadIdx.x / C2, j = threadIdx.x % C2;   // ln<16
    int n0 = blockIdx.x * 16;
    for (int idx = threadIdx.x; idx < 16 * 50; idx += 320) {
        int r = idx / 50, c = idx % 50;
        int n = n0 + r;
        unsigned u = (n < NN) ? h1b[(size_t)n * 50 + c] : 0u;
        sr[r][2 * c] = bf_lo(u);
        sr[r][2 * c + 1] = bf_hi(u);
    }
    __syncthreads();
    int n = n0 + ln;
    if (n < NN && ln < 16) {
        float acc = 0.f;
        #pragma unroll 4
        for (int k = 0; k < C1; ++k) acc += sr[ln][k] * sW[k * C2 + j];
        t2[(size_t)n * C2 + j] = acc;
    }
}

// ---------------- fused: agg2 (mean+bias+relu) + graph pool (atomic) ----------------
__global__ void k_agg2p(const float* __restrict__ t2, const int* __restrict__ row_ptr,
                        const int* __restrict__ elist, const float* __restrict__ bias,
                        const int* __restrict__ gid, float* __restrict__ hgs) {
    int ln = threadIdx.x / C2, c = threadIdx.x % C2;
    if (ln >= 12) return;
    int n = blockIdx.x * 12 + ln;
    if (n >= NN) return;
    int e0 = row_ptr[n], e1 = row_ptr[n + 1];
    float acc = 0.f;
    int e = e0;
    for (; e + 1 < e1; e += 2) {
        int s0 = elist[e], s1 = elist[e + 1];
        acc += t2[(size_t)s0 * C2 + c];
        acc += t2[(size_t)s1 * C2 + c];
    }
    for (; e < e1; ++e) acc += t2[(size_t)elist[e] * C2 + c];
    int deg = e1 - e0;
    float d = (float)(deg > 0 ? deg : 1);
    float v = acc / d + bias[c];
    v = v > 0.f ? v : 0.f;
    atomicAdd(&hgs[gid[n] * C2 + c], v);
}

// ---------------- fused per-graph tail: hg div (bsearch cnt) + attn head + d1ext prep ----------------
__global__ void k_headp(const float* __restrict__ hgs, const int* __restrict__ gid,
                        const float* __restrict__ desc2d,
                        const float* __restrict__ pgW, const float* __restrict__ pgb,
                        const float* __restrict__ p2W, const float* __restrict__ p2b,
                        const float* __restrict__ W2,
                        float* __restrict__ hg, float* __restrict__ d1ext) {
    __shared__ float shg[C2];
    __shared__ float sg[DHH];
    __shared__ float sa;
    int b = blockIdx.x, j = threadIdx.x;   // 64 threads
    int lo = 0, hi = NN;
    while (lo < hi) { int m = (lo + hi) >> 1; if (gid[m] < b) lo = m + 1; else hi = m; }
    int lo2 = lo, hi2 = NN;
    while (lo2 < hi2) { int m = (lo2 + hi2) >> 1; if (gid[m] < b + 1) lo2 = m + 1; else hi2 = m; }
    float dcnt = (float)(lo2 - lo);
    if (dcnt < 1.f) dcnt = 1.f;
    if (j < C2) {
        float v = hgs[b * C2 + j] / dcnt;
        hg[b * C2 + j] = v;
        shg[j] = v;
    }
    __syncthreads();
    float hgj = pgb[j];
    #pragma unroll
    for (int k = 0; k < C2; ++k) hgj += shg[k] * pgW[k * DHH + j];
    float hdj = p2b[j];
    #pragma unroll 4
    for (int k = 0; k < DD2; ++k) hdj += desc2d[b * DD2 + k] * p2W[k * DHH + j];
    sg[j] = hgj;
    __syncthreads();
    float tj = 0.f;
    #pragma unroll 4
    for (int k = 0; k < DHH; ++k) tj += sg[k] * W2[k * DHH + j];
    float v = tj * hdj;
    #pragma unroll
    for (int off = 32; off; off >>= 1) v += __shfl_xor(v, off, 64);
    if (j == 0) sa = 1.f / (1.f + expf(-v));
    __syncthreads();
    float a = sa;
    for (int k = j; k < KDP; k += 64) {
        float vv = (k < DD2) ? a * desc2d[b * DD2 + k] : (k == DD2 ? 1.f : 0.f);
        d1ext[b * KDP + k] = vv;
    }
}

// ---------------- fc1 via rank-1 factorization ----------------
__global__ __launch_bounds__(256, 2) void k_fc1(const float* __restrict__ d1ext,
                                                const float* __restrict__ W1,
                                                float* __restrict__ U) {
    __shared__ float S[64][KDP];
    const int i = blockIdx.y;
    const int bt = blockIdx.x >> 1;
    const int half = blockIdx.x & 1;
    const int tid = threadIdx.x;
    const int c = tid & 31;
    const int rg = tid >> 5;

    {
        const float4* srcp = (const float4*)(d1ext + (size_t)bt * 64 * KDP);
        float4* dstp = (float4*)&S[0][0];
        for (int idx = tid; idx < 64 * (KDP / 4); idx += 256) dstp[idx] = srcp[idx];
    }
    __syncthreads();

    float acc[8][2];
    #pragma unroll
    for (int r = 0; r < 8; ++r) { acc[r][0] = 0.f; acc[r][1] = 0.f; }

    const float* Wb = W1 + (size_t)i * (KD * HH1) + half * 64 + c;
    for (int k = 0; k < 200; k += 4) {
        const float* Wk = Wb + (size_t)k * HH1;
        float w0[2], w1[2], w2[2], w3[2];
        #pragma unroll
        for (int m = 0; m < 2; ++m) {
            w0[m] = Wk[32 * m];
            w1[m] = Wk[HH1 + 32 * m];
            w2[m] = Wk[2 * HH1 + 32 * m];
            w3[m] = Wk[3 * HH1 + 32 * m];
        }
        #pragma unroll
        for (int r = 0; r < 8; ++r) {
            float4 a4 = *(const float4*)&S[rg * 8 + r][k];
            #pragma unroll
            for (int m = 0; m < 2; ++m)
                acc[r][m] += a4.x * w0[m] + a4.y * w1[m] + a4.z * w2[m] + a4.w * w3[m];
        }
    }
    {
        const float* Wk = Wb + (size_t)200 * HH1;
        float wl0 = Wk[0], wl1 = Wk[32];
        #pragma unroll
        for (int r = 0; r < 8; ++r) {
            float av = S[rg * 8 + r][200];
            acc[r][0] += av * wl0;
            acc[r][1] += av * wl1;
        }
    }
    #pragma unroll
    for (int r = 0; r < 8; ++r) {
        int b = bt * 64 + rg * 8 + r;
        float* Ur = U + (size_t)b * NU + i * HH1 + half * 64 + c;
        Ur[0] = acc[r][0];
        Ur[32] = acc[r][1];
    }
}

__global__ void k_fc1b(const float* __restrict__ U, const float* __restrict__ hg,
                       float* __restrict__ o1) {
    int idx = blockIdx.x * 256 + threadIdx.x;   // 65536
    int b = idx >> 7, j = idx & 127;
    const float* Ub = U + (size_t)b * NU + j;
    const float* hgb = hg + b * C2;
    float acc = Ub[20 * HH1];
    #pragma unroll
    for (int i = 0; i < 20; ++i) acc += hgb[i] * Ub[i * HH1];
    o1[idx] = acc;
}

// ---------------- fc2 with in-block bn1 stats (no separate bnstats) ----------------
// grid 128 blocks x 128 threads; block handles 4 rows. Thread j computes column-j stats
// over all 512 rows (coalesced), then bn+relu+matvec for its rows.
__global__ __launch_bounds__(128) void k_fc2(const float* __restrict__ o1,
                                             const float* __restrict__ g,
                                             const float* __restrict__ beta,
                                             const float* __restrict__ W,
                                             float* __restrict__ o2) {
    __shared__ float r[HH1];
    __shared__ float part[4][HH2];
    const int tid = threadIdx.x;   // 128
    float s = 0.f, s2 = 0.f;
    for (int b = 0; b < NB; ++b) {
        float v = o1[b * HH1 + tid];
        s += v; s2 += v * v;
    }
    float mu = s / NB;
    float rstd = rsqrtf(s2 / NB - mu * mu + 1e-5f);
    float scale = rstd * g[tid];
    float shift = beta[tid] - mu * scale;
    const int m = tid & 31, p = tid >> 5;
    for (int q = 0; q < 4; ++q) {
        int b = blockIdx.x * 4 + q;
        float v = o1[b * HH1 + tid];
        __syncthreads();
        r[tid] = fmaxf(v * scale + shift, 0.f);
        __syncthreads();
        float acc = 0.f;
        #pragma unroll 4
        for (int j = p * 32; j < p * 32 + 32; ++j) acc += r[j] * W[j * HH2 + m];
        part[p][m] = acc;
        __syncthreads();
        if (tid < HH2) o2[b * HH2 + tid] = part[0][tid] + part[1][tid] + part[2][tid] + part[3][tid];
    }
}

// ---------------- final: in-block bn2 stats + relu + fc3 ----------------
__global__ __launch_bounds__(512) void k_final(const float* __restrict__ o2,
                                               const float* __restrict__ g,
                                               const float* __restrict__ beta,
                                               const float* __restrict__ W3,
                                               const float* __restrict__ b3,
                                               float* __restrict__ out) {
    __shared__ float ps[16][HH2], ps2[16][HH2];
    __shared__ float sscale[HH2], sshift[HH2];
    const int tid = threadIdx.x;    // 512
    const int gq = tid >> 5, m = tid & 31;
    float s = 0.f, s2 = 0.f;
    for (int rr = 0; rr < 32; ++rr) {
        float v = o2[(gq * 32 + rr) * HH2 + m];
        s += v; s2 += v * v;
    }
    ps[gq][m] = s; ps2[gq][m] = s2;
    __syncthreads();
    if (tid < HH2) {
        float ts = 0.f, ts2 = 0.f;
        #pragma unroll
        for (int q = 0; q < 16; ++q) { ts += ps[q][tid]; ts2 += ps2[q][tid]; }
        float mu = ts / NB;
        float rstd = rsqrtf(ts2 / NB - mu * mu + 1e-5f);
        float scale = rstd * g[tid];
        sscale[tid] = scale;
        sshift[tid] = beta[tid] - mu * scale;
    }
    __syncthreads();
    float acc = b3[0];
    #pragma unroll 4
    for (int mm = 0; mm < HH2; ++mm) {
        float v = o2[tid * HH2 + mm];
        acc += fmaxf(v * sscale[mm] + sshift[mm], 0.f) * W3[mm];
    }
    out[tid] = acc;
}

extern "C" void kernel_launch(void* const* d_in, const int* in_sizes, int n_in,
                              void* d_out, int out_size, void* d_ws, size_t ws_size,
                              hipStream_t stream) {
    const float* feat   = (const float*)d_in[0];
    const float* desc2d = (const float*)d_in[1];
    const float* gc1W = (const float*)d_in[3];
    const float* gc1b = (const float*)d_in[4];
    const float* gc2W = (const float*)d_in[5];
    const float* gc2b = (const float*)d_in[6];
    const float* pgW  = (const float*)d_in[7];
    const float* pgb  = (const float*)d_in[8];
    const float* p2W  = (const float*)d_in[9];
    const float* p2b  = (const float*)d_in[10];
    const float* W2   = (const float*)d_in[11];
    const float* fc1W = (const float*)d_in[12];
    const float* fc2W = (const float*)d_in[14];
    const float* fc3W = (const float*)d_in[16];
    const float* fc3b = (const float*)d_in[17];
    const float* bn1g = (const float*)d_in[18];
    const float* bn1b = (const float*)d_in[19];
    const float* bn2g = (const float*)d_in[20];
    const float* bn2b = (const float*)d_in[21];
    const int* src = (const int*)d_in[22];
    const int* dst = (const int*)d_in[23];
    const int* gid = (const int*)d_in[24];
    float* out = (float*)d_out;

    char* ws = (char*)d_ws;
    size_t off = 0;
    auto alloc = [&](size_t nb) {
        void* p = ws + off;
        off = (off + nb + 255) & ~(size_t)255;
        return p;
    };
    unsigned char* t1f8 = (unsigned char*)alloc((size_t)NN * PS1);   // 6.4 MB fp8, 128B rows
    unsigned* h1b = (unsigned*)alloc((size_t)NN * 50 * 4);           // 10 MB packed bf16
    float* t2    = (float*)alloc((size_t)NN * C2 * 4);               // 4 MB
    int* cnt_in  = (int*)alloc((size_t)NN * 4);
    int* rp_part = (int*)alloc((size_t)NN * 4);
    int* row_ptr = (int*)alloc((size_t)(NN + 1) * 4);
    int* pos     = (int*)alloc((size_t)NE * 4);
    int* elist   = (int*)alloc((size_t)NE * 4);
    int* bsum    = (int*)alloc((size_t)256 * 4);
    int* dcount  = (int*)alloc(256);
    unsigned short* Bf = (unsigned short*)alloc((size_t)NCT * 4 * 64 * 16);  // 28 KB
    float* hgs   = (float*)alloc((size_t)NB * C2 * 4);
    float* hg    = (float*)alloc((size_t)NB * C2 * 4);
    float* o1    = (float*)alloc((size_t)NB * HH1 * 4);
    float* o2    = (float*)alloc((size_t)NB * HH2 * 4);
    // fc1 scratch aliases t1f8 (dead after k_agg1): 5.5 MB + 0.42 MB < 6.4 MB
    float* U     = (float*)t1f8;
    float* d1ext = U + (size_t)NB * NU;

    k_packB_init<<<SCB, 256, 0, stream>>>(gc1W, Bf, cnt_in, hgs, dcount);
    k_front<<<GB1 + FPB, 256, 0, stream>>>(feat, Bf, t1f8, dst, cnt_in, pos);
    k_scan<<<SCB, 256, 0, stream>>>(cnt_in, rp_part, bsum, row_ptr, dcount);
    k_scat3<<<(NE + 255) / 256, 256, 0, stream>>>(src, dst, rp_part, bsum, pos, elist, row_ptr);

    k_agg1<<<(NN + 3) / 4, 256, 0, stream>>>(t1f8, row_ptr, elist, gc1b, h1b);
    k_gemm2<<<(NN + 15) / 16, 320, 0, stream>>>(h1b, gc2W, t2);
    k_agg2p<<<(NN + 11) / 12, 256, 0, stream>>>(t2, row_ptr, elist, gc2b, gid, hgs);

    k_headp<<<NB, 64, 0, stream>>>(hgs, gid, desc2d, pgW, pgb, p2W, p2b, W2, hg, d1ext);

    dim3 g1(16, 21);
    k_fc1<<<g1, 256, 0, stream>>>(d1ext, fc1W, U);
    k_fc1b<<<NB * HH1 / 256, 256, 0, stream>>>(U, hg, o1);

    k_fc2<<<NB / 4, 128, 0, stream>>>(o1, bn1g, bn1b, fc2W, o2);
    k_final<<<1, 512, 0, stream>>>(o2, bn2g, bn2b, fc3W, fc3b, out);
}